// Round 1
// baseline (567.868 us; speedup 1.0000x reference)
//
#include <hip/hip_runtime.h>

#define HIDDEN 128
#define TSTEPS 512
#define NFUT 50
#define BR 16          // batch rows per block
#define THREADS 256    // 4 waves, 1 per SIMD: ILP (2 MFMA sets/wave) replaces TLP
#define HPITCH 136     // h row pitch in bf16 (272B rows: 16B-aligned for b128)

typedef __bf16 bf16x8 __attribute__((ext_vector_type(8)));
typedef float floatx4 __attribute__((ext_vector_type(4)));
typedef float f32x2 __attribute__((ext_vector_type(2)));

union B8 { int4 i; bf16x8 v; };

#if defined(__has_builtin)
#  if __has_builtin(__builtin_amdgcn_exp2f)
#    define EXP2F(x) __builtin_amdgcn_exp2f(x)
#  else
#    define EXP2F(x) exp2f(x)
#  endif
#  if __has_builtin(__builtin_amdgcn_rcpf)
#    define RCPF(x) __builtin_amdgcn_rcpf(x)
#  else
#    define RCPF(x) (1.0f / (x))
#  endif
#else
#  define EXP2F(x) exp2f(x)
#  define RCPF(x) (1.0f / (x))
#endif

#define L2E  1.4426950408889634f
#define L2E2 2.8853900817779268f

__global__ __launch_bounds__(THREADS, 1)
void lstm_forecast_kernel(const float* __restrict__ x,
                          const float* __restrict__ W_ih,
                          const float* __restrict__ W_hh,
                          const float* __restrict__ b_ih,
                          const float* __restrict__ b_hh,
                          const float* __restrict__ fc_w,
                          const float* __restrict__ fc_b,
                          float* __restrict__ out) {
    // LDS: xa 64KB + h 8.5KB + fcw 1KB ~= 74KB -> 1 block/CU (grid == 256 anyway)
    __shared__ __align__(16) uint2  xa[TSTEPS * BR];        // (x0h,x1h),(x0r,x1r) bf16 splits
    __shared__ __align__(16) __bf16 h_lds[2][BR * HPITCH];  // double-buffered h
    __shared__ __align__(16) float  fcw_lds[2][HIDDEN];

    const int tid  = threadIdx.x;
    const int wave = tid >> 6;          // 0..3
    const int lane = tid & 63;
    const int quad = lane >> 4;
    const int l15  = lane & 15;
    const int rb   = blockIdx.x * BR;

    if (tid < 256) fcw_lds[tid >> 7][tid & 127] = fc_w[tid];

    // ---- stage x as bf16 hi/lo splits: xa[t][row] ----
    {
        const int row = tid & 15;
        for (int tb = tid >> 4; tb < TSTEPS; tb += THREADS >> 4) {
            float2 xv = *(const float2*)&x[(size_t)(rb + row) * (2 * TSTEPS) + tb * 2];
            __bf16 x0h = (__bf16)xv.x, x1h = (__bf16)xv.y;
            __bf16 x0r = (__bf16)(xv.x - (float)x0h);
            __bf16 x1r = (__bf16)(xv.y - (float)x1h);
            uint2 d;
            d.x = (unsigned)__builtin_bit_cast(unsigned short, x0h) |
                  ((unsigned)__builtin_bit_cast(unsigned short, x1h) << 16);
            d.y = (unsigned)__builtin_bit_cast(unsigned short, x0r) |
                  ((unsigned)__builtin_bit_cast(unsigned short, x1r) << 16);
            xa[tb * BR + row] = d;
        }
    }
    for (int i = tid; i < BR * HPITCH; i += THREADS) h_lds[0][i] = (__bf16)0.0f;

    // ---- weights -> registers, pre-scaled so MFMA outputs are exp2-ready ----
    // gate scale: i,f,o -> -log2(e); g -> -2*log2(e)
    // Transposed mapping: bfrag is the MFMA *A* operand (m = gate col = lane&15),
    // af (h rows) is the *B* operand. Per-lane data identical to previous kernel;
    // only the operand ORDER in the intrinsic changes.
    bf16x8 bfrag[2][4][4];   // [set][gate][kchunk] scaled W_hh (later W_eff)
    B8 bfx[2][4];            // scaled x-weight+bias fragments (quad0 k-slots only)
    float gs[4];
    const float fcb0 = fc_b[0], fcb1 = fc_b[1];
#pragma unroll
    for (int g = 0; g < 4; ++g) gs[g] = (g == 2) ? -L2E2 : -L2E;
#pragma unroll
    for (int s = 0; s < 2; ++s) {
        const int ub = wave * 32 + s * 16 + l15;   // this lane's gate col (A-layout)
#pragma unroll
        for (int g = 0; g < 4; ++g) {
            const int cg = g * HIDDEN + ub;
            const float w0 = W_ih[cg * 2 + 0];
            const float w1 = W_ih[cg * 2 + 1];
            const float bs = b_ih[cg] + b_hh[cg];
#pragma unroll
            for (int ks = 0; ks < 4; ++ks) {
                const float* wp = W_hh + (size_t)cg * HIDDEN + ks * 32 + quad * 8;
                bf16x8 bb;
#pragma unroll
                for (int j = 0; j < 8; ++j) bb[j] = (__bf16)(gs[g] * wp[j]);
                bfrag[s][g][ks] = bb;
            }
            B8 t; t.i = make_int4(0, 0, 0, 0);
            if (quad == 0) {
                const float w0s = gs[g] * w0, w1s = gs[g] * w1, bss = gs[g] * bs;
                __bf16 w0h = (__bf16)w0s, w1h = (__bf16)w1s;
                __bf16 w0l = (__bf16)(w0s - (float)w0h);
                __bf16 w1l = (__bf16)(w1s - (float)w1h);
                __bf16 bh  = (__bf16)bss;
                __bf16 bl  = (__bf16)(bss - (float)bh);
                bf16x8 bv = {w0h, w1h, bh, bl, w0h, w1h, w0l, w1l};
                t.v = bv;
            }
            bfx[s][g] = t;
        }
    }

    const unsigned ones2 = 0x3F803F80u;  // bf16(1.0) x2 (A rows are 0 off-quad0)
    const int hrow = l15 * HPITCH;       // this thread's batch row (C-layout)
    const int c0   = wave * 32 + quad * 4;   // set0 hidden-col base (C-layout)

    // cell state: [set][pair], each pair = 2 cells (row l15, consecutive cols)
    f32x2 cst[2][2] = {{{0.f, 0.f}, {0.f, 0.f}}, {{0.f, 0.f}, {0.f, 0.f}}};

    auto mk = [](float a, float b) { f32x2 r; r.x = a; r.y = b; return r; };

    // elementwise for one packed pair; 5 exp + 1 rcp per cell (pairwise-batched rcp).
    // Returns 2 packed bf16 h-values.
    auto ewPair = [&](f32x2 ap0, f32x2 ap1, f32x2 ap2, f32x2 ap3, f32x2& c) -> unsigned {
        f32x2 ea, eb, ec;
        ea.x = EXP2F(ap0.x); ea.y = EXP2F(ap0.y);   // e^-i (scaled)
        eb.x = EXP2F(ap2.x); eb.y = EXP2F(ap2.y);   // e^-2g
        ec.x = EXP2F(ap1.x); ec.y = EXP2F(ap1.y);   // e^-f
        const f32x2 A1 = 1.f + ea, B1 = 1.f + eb, C1 = 1.f + ec;
        const f32x2 P  = A1 * B1;
        const f32x2 PC = P * C1;
        f32x2 R;                                    // batched: 1 rcp for the pair
        {
            const float I = RCPF(PC.x * PC.y);
            R.x = I * PC.y;
            R.y = I * PC.x;
        }
        const f32x2 sfv = P * R;                    // sigmoid(f)
        const f32x2 igv = (1.f - eb) * (C1 * R);    // sigmoid(i)*tanh(g)
        const f32x2 cn  = sfv * c + igv;
        c = cn;
        const f32x2 am = -L2E2 * cn;
        f32x2 ed, eo;
        ed.x = EXP2F(fminf(am.x, 29.f));            // c clamped at -10 (tanh err < 4e-9)
        ed.y = EXP2F(fminf(am.y, 29.f));
        eo.x = EXP2F(ap3.x); eo.y = EXP2F(ap3.y);   // e^-o
        const f32x2 E = (1.f + ed) * (1.f + eo);
        f32x2 R2;                                   // batched: 1 rcp for the pair
        {
            const float J = RCPF(E.x * E.y);
            R2.x = J * E.y;
            R2.y = J * E.x;
        }
        const f32x2 hn = (1.f - ed) * R2;           // sigmoid(o)*tanh(c)
        return (unsigned)__builtin_bit_cast(unsigned short, (__bf16)hn.x)
             | ((unsigned)__builtin_bit_cast(unsigned short, (__bf16)hn.y) << 16);
    };

    // Encode cell: transposed MFMA (A = weights, B = h/x), two sets pipelined:
    // set1 MFMAs interleaved with set0 elementwise so matrix + VALU pipes overlap.
    auto cellE = [&](const __bf16* hs, __bf16* hd, int t) {
        const uint2 xd = xa[t * BR + l15];            // quad-broadcast, conflict-free
        B8 xf; xf.i = make_int4((int)xd.x, (int)ones2, (int)xd.y, (int)xd.x);
        bf16x8 af[4];                                 // B operand: shared by both sets
#pragma unroll
        for (int ks = 0; ks < 4; ++ks)
            af[ks] = *(const bf16x8*)&hs[hrow + ks * 32 + quad * 8];
        const floatx4 z = {0.f, 0.f, 0.f, 0.f};
        floatx4 a0[4], a1[4];
        // ---- set 0: full 20 MFMAs ----
#pragma unroll
        for (int g = 0; g < 4; ++g)
            a0[g] = __builtin_amdgcn_mfma_f32_16x16x32_bf16(bfx[0][g].v, xf.v, z, 0, 0, 0);
#pragma unroll
        for (int ks = 0; ks < 4; ++ks)
#pragma unroll
            for (int g = 0; g < 4; ++g)
                a0[g] = __builtin_amdgcn_mfma_f32_16x16x32_bf16(bfrag[0][g][ks], af[ks], a0[g], 0, 0, 0);
        // ---- set 1 MFMAs overlap set 0 elementwise ----
#pragma unroll
        for (int g = 0; g < 4; ++g)
            a1[g] = __builtin_amdgcn_mfma_f32_16x16x32_bf16(bfx[1][g].v, xf.v, z, 0, 0, 0);
#pragma unroll
        for (int ks = 0; ks < 2; ++ks)
#pragma unroll
            for (int g = 0; g < 4; ++g)
                a1[g] = __builtin_amdgcn_mfma_f32_16x16x32_bf16(bfrag[1][g][ks], af[ks], a1[g], 0, 0, 0);
        const unsigned lo0 = ewPair(mk(a0[0][0], a0[0][1]), mk(a0[1][0], a0[1][1]),
                                    mk(a0[2][0], a0[2][1]), mk(a0[3][0], a0[3][1]), cst[0][0]);
#pragma unroll
        for (int ks = 2; ks < 4; ++ks)
#pragma unroll
            for (int g = 0; g < 4; ++g)
                a1[g] = __builtin_amdgcn_mfma_f32_16x16x32_bf16(bfrag[1][g][ks], af[ks], a1[g], 0, 0, 0);
        const unsigned hi0 = ewPair(mk(a0[0][2], a0[0][3]), mk(a0[1][2], a0[1][3]),
                                    mk(a0[2][2], a0[2][3]), mk(a0[3][2], a0[3][3]), cst[0][1]);
        { uint2 w; w.x = lo0; w.y = hi0; *(uint2*)&hd[hrow + c0] = w; }        // 4 cols, 1 b64
        const unsigned lo1 = ewPair(mk(a1[0][0], a1[0][1]), mk(a1[1][0], a1[1][1]),
                                    mk(a1[2][0], a1[2][1]), mk(a1[3][0], a1[3][1]), cst[1][0]);
        const unsigned hi1 = ewPair(mk(a1[0][2], a1[0][3]), mk(a1[1][2], a1[1][3]),
                                    mk(a1[2][2], a1[2][3]), mk(a1[3][2], a1[3][3]), cst[1][1]);
        { uint2 w; w.x = lo1; w.y = hi1; *(uint2*)&hd[hrow + c0 + 16] = w; }
        __syncthreads();
    };

    __syncthreads();

    // ================= encode: 512 steps =================
    for (int t = 0; t < TSTEPS; t += 2) {
        cellE(h_lds[0], h_lds[1], t);
        cellE(h_lds[1], h_lds[0], t + 1);
    }

    // ========== transition: fold fc into weights =========
    // W_eff = gs*(W_hh + W_ih*fc_w) ; b_eff = gs*(b + W_ih*fc_b)
    // bias is needed in C-layout (cols quad*4+r) -> redistribute via __shfl.
    floatx4 bs2v[2][4];
#pragma unroll
    for (int s = 0; s < 2; ++s) {
        const int ub = wave * 32 + s * 16 + l15;
#pragma unroll
        for (int g = 0; g < 4; ++g) {
            const int cg = g * HIDDEN + ub;
            const float wi0 = W_ih[cg * 2 + 0];
            const float wi1 = W_ih[cg * 2 + 1];
            const float bs  = b_ih[cg] + b_hh[cg];
            const float b2  = gs[g] * (bs + wi0 * fcb0 + wi1 * fcb1);  // per-lane (A-layout)
#pragma unroll
            for (int ks = 0; ks < 4; ++ks) {
                const int k0 = ks * 32 + quad * 8;
                bf16x8 bb = bfrag[s][g][ks];
#pragma unroll
                for (int j = 0; j < 8; ++j) {
                    const float wv = (float)bb[j] + gs[g] * (wi0 * fcw_lds[0][k0 + j]
                                                          + wi1 * fcw_lds[1][k0 + j]);
                    bb[j] = (__bf16)wv;
                }
                bfrag[s][g][ks] = bb;
            }
            floatx4 v;
#pragma unroll
            for (int r = 0; r < 4; ++r) v[r] = __shfl(b2, quad * 4 + r);  // C-layout bias
            bs2v[s][g] = v;
        }
    }

    auto cellF = [&](const __bf16* hs, __bf16* hd) {
        bf16x8 af[4];
#pragma unroll
        for (int ks = 0; ks < 4; ++ks)
            af[ks] = *(const bf16x8*)&hs[hrow + ks * 32 + quad * 8];
        floatx4 a0[4], a1[4];
#pragma unroll
        for (int g = 0; g < 4; ++g) a0[g] = bs2v[0][g];   // exact fp32 scaled bias
#pragma unroll
        for (int ks = 0; ks < 4; ++ks)
#pragma unroll
            for (int g = 0; g < 4; ++g)
                a0[g] = __builtin_amdgcn_mfma_f32_16x16x32_bf16(bfrag[0][g][ks], af[ks], a0[g], 0, 0, 0);
#pragma unroll
        for (int g = 0; g < 4; ++g) a1[g] = bs2v[1][g];
#pragma unroll
        for (int ks = 0; ks < 2; ++ks)
#pragma unroll
            for (int g = 0; g < 4; ++g)
                a1[g] = __builtin_amdgcn_mfma_f32_16x16x32_bf16(bfrag[1][g][ks], af[ks], a1[g], 0, 0, 0);
        const unsigned lo0 = ewPair(mk(a0[0][0], a0[0][1]), mk(a0[1][0], a0[1][1]),
                                    mk(a0[2][0], a0[2][1]), mk(a0[3][0], a0[3][1]), cst[0][0]);
#pragma unroll
        for (int ks = 2; ks < 4; ++ks)
#pragma unroll
            for (int g = 0; g < 4; ++g)
                a1[g] = __builtin_amdgcn_mfma_f32_16x16x32_bf16(bfrag[1][g][ks], af[ks], a1[g], 0, 0, 0);
        const unsigned hi0 = ewPair(mk(a0[0][2], a0[0][3]), mk(a0[1][2], a0[1][3]),
                                    mk(a0[2][2], a0[2][3]), mk(a0[3][2], a0[3][3]), cst[0][1]);
        { uint2 w; w.x = lo0; w.y = hi0; *(uint2*)&hd[hrow + c0] = w; }
        const unsigned lo1 = ewPair(mk(a1[0][0], a1[0][1]), mk(a1[1][0], a1[1][1]),
                                    mk(a1[2][0], a1[2][1]), mk(a1[3][0], a1[3][1]), cst[1][0]);
        const unsigned hi1 = ewPair(mk(a1[0][2], a1[0][3]), mk(a1[1][2], a1[1][3]),
                                    mk(a1[2][2], a1[2][3]), mk(a1[3][2], a1[3][3]), cst[1][1]);
        { uint2 w; w.x = lo1; w.y = hi1; *(uint2*)&hd[hrow + c0 + 16] = w; }
        __syncthreads();
    };

    // y output only (no feedback): wave0 computes while others run MFMA
    auto emitY = [&](const __bf16* hs, int f) {
        if (wave == 0) {
            const int r = lane & 15, seg = lane >> 4;
            const __bf16* hp = &hs[r * HPITCH + seg * 32];
            float p0 = 0.f, p1 = 0.f;
#pragma unroll
            for (int js = 0; js < 4; ++js) {
                bf16x8 hv = *(const bf16x8*)&hp[js * 8];
                const float4* f0 = (const float4*)&fcw_lds[0][seg * 32 + js * 8];
                const float4* f1 = (const float4*)&fcw_lds[1][seg * 32 + js * 8];
                float4 a0 = f0[0], b0 = f0[1], a1 = f1[0], b1 = f1[1];
                p0 += (float)hv[0]*a0.x + (float)hv[1]*a0.y + (float)hv[2]*a0.z + (float)hv[3]*a0.w
                    + (float)hv[4]*b0.x + (float)hv[5]*b0.y + (float)hv[6]*b0.z + (float)hv[7]*b0.w;
                p1 += (float)hv[0]*a1.x + (float)hv[1]*a1.y + (float)hv[2]*a1.z + (float)hv[3]*a1.w
                    + (float)hv[4]*b1.x + (float)hv[5]*b1.y + (float)hv[6]*b1.z + (float)hv[7]*b1.w;
            }
            p0 += __shfl_xor(p0, 16); p0 += __shfl_xor(p0, 32);
            p1 += __shfl_xor(p1, 16); p1 += __shfl_xor(p1, 32);
            if (seg == 0) {
                float* op = &out[(size_t)(rb + r) * (2 * NFUT) + f * 2];
                op[0] = p0 + fcb0;
                op[1] = p1 + fcb1;
            }
        }
    };

    // ================= forecast: 50 steps ================
    for (int f = 0; f < NFUT; f += 2) {
        emitY(h_lds[0], f);
        cellF(h_lds[0], h_lds[1]);
        emitY(h_lds[1], f + 1);
        cellF(h_lds[1], h_lds[0]);
    }
}

extern "C" void kernel_launch(void* const* d_in, const int* in_sizes, int n_in,
                              void* d_out, int out_size, void* d_ws, size_t ws_size,
                              hipStream_t stream) {
    const float* x    = (const float*)d_in[0];
    const float* W_ih = (const float*)d_in[1];
    const float* W_hh = (const float*)d_in[2];
    const float* b_ih = (const float*)d_in[3];
    const float* b_hh = (const float*)d_in[4];
    const float* fc_w = (const float*)d_in[5];
    const float* fc_b = (const float*)d_in[6];
    float* out = (float*)d_out;

    const int B = in_sizes[0] / (TSTEPS * 2);   // 4096
    const int grid = B / BR;                    // 256 blocks, 1 per CU
    lstm_forecast_kernel<<<grid, THREADS, 0, stream>>>(x, W_ih, W_hh, b_ih, b_hh, fc_w, fc_b, out);
}

// Round 2
// 520.764 us; speedup vs baseline: 1.0905x; 1.0905x over previous
//
#include <hip/hip_runtime.h>

#define HIDDEN 128
#define TSTEPS 512
#define NFUT 50
#define BR 16          // batch rows per block
#define THREADS 512    // 8 waves, 2/SIMD: TLP latency-hiding + per-gate MFMA/exp interleave
#define HPITCH 136     // h row pitch in bf16 (272B rows: 16B-aligned for b128)

typedef __bf16 bf16x8 __attribute__((ext_vector_type(8)));
typedef float floatx4 __attribute__((ext_vector_type(4)));
typedef float f32x2 __attribute__((ext_vector_type(2)));

#if defined(__has_builtin)
#  if __has_builtin(__builtin_amdgcn_exp2f)
#    define EXP2F(x) __builtin_amdgcn_exp2f(x)
#  else
#    define EXP2F(x) exp2f(x)
#  endif
#  if __has_builtin(__builtin_amdgcn_rcpf)
#    define RCPF(x) __builtin_amdgcn_rcpf(x)
#  else
#    define RCPF(x) (1.0f / (x))
#  endif
#else
#  define EXP2F(x) exp2f(x)
#  define RCPF(x) (1.0f / (x))
#endif

#define L2E  1.4426950408889634f
#define L2E2 2.8853900817779268f

__global__ __launch_bounds__(THREADS, 2)
void lstm_forecast_kernel(const float* __restrict__ x,
                          const float* __restrict__ W_ih,
                          const float* __restrict__ W_hh,
                          const float* __restrict__ b_ih,
                          const float* __restrict__ b_hh,
                          const float* __restrict__ fc_w,
                          const float* __restrict__ fc_b,
                          float* __restrict__ out) {
    // LDS: xa 64KB + h 8.5KB + fcw 1KB ~= 74KB -> 1 block/CU
    __shared__ __align__(16) float2 xa[TSTEPS * BR];        // fp32 x (exact C-init, no bf16 split)
    __shared__ __align__(16) __bf16 h_lds[2][BR * HPITCH];  // double-buffered h
    __shared__ __align__(16) float  fcw_lds[2][HIDDEN];

    const int tid  = threadIdx.x;
    const int wave = tid >> 6;          // 0..7, SIMD = wave & 3 (2 waves share a SIMD)
    const int lane = tid & 63;
    const int quad = lane >> 4;
    const int l15  = lane & 15;
    const int rb   = blockIdx.x * BR;

    if (tid < 256) fcw_lds[tid >> 7][tid & 127] = fc_w[tid];

    // ---- stage x as fp32: xa[t][row] ----
    {
        const int row = tid & 15;
        for (int tb = tid >> 4; tb < TSTEPS; tb += THREADS >> 4)
            xa[tb * BR + row] = *(const float2*)&x[(size_t)(rb + row) * (2 * TSTEPS) + tb * 2];
    }
    for (int i = tid; i < BR * HPITCH; i += THREADS) h_lds[0][i] = (__bf16)0.0f;

    // ---- weights -> registers, pre-scaled so MFMA outputs are exp2-ready ----
    // gate scale: i,f,o -> -log2(e); g -> -2*log2(e)
    // Transposed MFMA: bfrag = A operand (m = gate col = wave*16 + l15), h = B operand.
    // C layout: n(=lane&15) = batch row, m(=quad*4+reg) = gate-col offset.
    bf16x8 bfrag[4][4];          // [gate][kchunk] scaled W_hh (later W_eff)
    floatx4 w0c[4], w1c[4], bc[4];  // C-layout gs-scaled W_ih cols + bias (for fp32 acc init)
    floatx4 beff[4];                // forecast-phase bias (filled at transition)
    float gs[4];
    const float fcb0 = fc_b[0], fcb1 = fc_b[1];
#pragma unroll
    for (int g = 0; g < 4; ++g) gs[g] = (g == 2) ? -L2E2 : -L2E;
    const int ub    = wave * 16 + l15;        // A-layout gate col (weights)
    const int cbase = wave * 16 + quad * 4;   // C-layout gate-col base (acc/h-write)
#pragma unroll
    for (int g = 0; g < 4; ++g) {
#pragma unroll
        for (int ks = 0; ks < 4; ++ks) {
            const float* wp = W_hh + (size_t)(g * HIDDEN + ub) * HIDDEN + ks * 32 + quad * 8;
            bf16x8 bb;
#pragma unroll
            for (int j = 0; j < 8; ++j) bb[j] = (__bf16)(gs[g] * wp[j]);
            bfrag[g][ks] = bb;
        }
        floatx4 v0, v1, vb;
#pragma unroll
        for (int r = 0; r < 4; ++r) {
            const int cg = g * HIDDEN + cbase + r;
            v0[r] = gs[g] * W_ih[cg * 2 + 0];
            v1[r] = gs[g] * W_ih[cg * 2 + 1];
            vb[r] = gs[g] * (b_ih[cg] + b_hh[cg]);
        }
        w0c[g] = v0; w1c[g] = v1; bc[g] = vb;
    }

    const int hrow = l15 * HPITCH;
    f32x2 cst[2] = {{0.f, 0.f}, {0.f, 0.f}};   // cell state: pair p = cols cbase+2p..+1

    auto pk2 = [](f32x2 hn) -> unsigned {
        return (unsigned)__builtin_bit_cast(unsigned short, (__bf16)hn.x)
             | ((unsigned)__builtin_bit_cast(unsigned short, (__bf16)hn.y) << 16);
    };

    // Core cell: acc arrives pre-initialized with gs*(W_ih*x + b) in exact fp32.
    // Per-gate interleave: [4 MFMA][4 exp] x4 so the sibling wave's MFMA quartets
    // fill the matrix pipe while this wave runs exps. Everything not needing
    // gate-o (incl. tanh(c) exp) is hoisted before gate-o's MFMAs.
    auto cellCore = [&](const __bf16* hs, __bf16* hd,
                        floatx4 a0, floatx4 a1, floatx4 a2, floatx4 a3) {
        bf16x8 af[4];
#pragma unroll
        for (int ks = 0; ks < 4; ++ks)
            af[ks] = *(const bf16x8*)&hs[hrow + ks * 32 + quad * 8];
        // gate i
#pragma unroll
        for (int ks = 0; ks < 4; ++ks)
            a0 = __builtin_amdgcn_mfma_f32_16x16x32_bf16(bfrag[0][ks], af[ks], a0, 0, 0, 0);
        floatx4 ea;
#pragma unroll
        for (int r = 0; r < 4; ++r) ea[r] = EXP2F(a0[r]);
        // gate f
#pragma unroll
        for (int ks = 0; ks < 4; ++ks)
            a1 = __builtin_amdgcn_mfma_f32_16x16x32_bf16(bfrag[1][ks], af[ks], a1, 0, 0, 0);
        floatx4 ec;
#pragma unroll
        for (int r = 0; r < 4; ++r) ec[r] = EXP2F(a1[r]);
        // gate g
#pragma unroll
        for (int ks = 0; ks < 4; ++ks)
            a2 = __builtin_amdgcn_mfma_f32_16x16x32_bf16(bfrag[2][ks], af[ks], a2, 0, 0, 0);
        floatx4 eb;
#pragma unroll
        for (int r = 0; r < 4; ++r) eb[r] = EXP2F(a2[r]);
        // partial combine (independent of gate o): c_new + tanh(c) exp
        f32x2 edp[2];
#pragma unroll
        for (int p = 0; p < 2; ++p) {
            const f32x2 eap = {ea[2 * p], ea[2 * p + 1]};   // e^-i
            const f32x2 ebp = {eb[2 * p], eb[2 * p + 1]};   // e^-2g
            const f32x2 ecp = {ec[2 * p], ec[2 * p + 1]};   // e^-f
            const f32x2 A1 = 1.f + eap, B1 = 1.f + ebp, C1 = 1.f + ecp;
            const f32x2 P  = A1 * B1;
            const f32x2 PC = P * C1;
            f32x2 R;                                        // batched: 1 rcp per pair
            { const float I = RCPF(PC.x * PC.y); R.x = I * PC.y; R.y = I * PC.x; }
            const f32x2 sfv = P * R;                        // sigmoid(f)
            const f32x2 igv = (1.f - ebp) * (C1 * R);       // sigmoid(i)*tanh(g)
            const f32x2 cn  = sfv * cst[p] + igv;
            cst[p] = cn;
            const f32x2 am = -L2E2 * cn;
            edp[p].x = EXP2F(fminf(am.x, 29.f));            // c clamped at -10 (tanh err < 4e-9)
            edp[p].y = EXP2F(fminf(am.y, 29.f));
        }
        // gate o (its MFMAs overlap the partial combine of the sibling wave)
#pragma unroll
        for (int ks = 0; ks < 4; ++ks)
            a3 = __builtin_amdgcn_mfma_f32_16x16x32_bf16(bfrag[3][ks], af[ks], a3, 0, 0, 0);
        floatx4 eo;
#pragma unroll
        for (int r = 0; r < 4; ++r) eo[r] = EXP2F(a3[r]);
        // final combine: only the o-dependent tail remains after the last MFMA
        unsigned wArr[2];
#pragma unroll
        for (int p = 0; p < 2; ++p) {
            const f32x2 eop = {eo[2 * p], eo[2 * p + 1]};
            const f32x2 E = (1.f + edp[p]) * (1.f + eop);
            f32x2 R2;                                       // batched: 1 rcp per pair
            { const float J = RCPF(E.x * E.y); R2.x = J * E.y; R2.y = J * E.x; }
            const f32x2 hn = (1.f - edp[p]) * R2;           // sigmoid(o)*tanh(c)
            wArr[p] = pk2(hn);
        }
        uint2 wv; wv.x = wArr[0]; wv.y = wArr[1];
        *(uint2*)&hd[hrow + cbase] = wv;                    // 4 cols, one b64
        __syncthreads();
    };

    // Encode cell: exact fp32 acc init gs*(b + w0*x0 + w1*x1) replaces the x-MFMAs
    // (-20% matrix work; init VALU hides under the MFMA phase).
    auto cellE = [&](const __bf16* hs, __bf16* hd, int t) {
        const float2 xv = xa[t * BR + l15];                 // quad-broadcast, conflict-free
        floatx4 a0 = bc[0] + w0c[0] * xv.x + w1c[0] * xv.y;
        floatx4 a1 = bc[1] + w0c[1] * xv.x + w1c[1] * xv.y;
        floatx4 a2 = bc[2] + w0c[2] * xv.x + w1c[2] * xv.y;
        floatx4 a3 = bc[3] + w0c[3] * xv.x + w1c[3] * xv.y;
        cellCore(hs, hd, a0, a1, a2, a3);
    };

    __syncthreads();

    // ================= encode: 512 steps =================
    for (int t = 0; t < TSTEPS; t += 2) {
        cellE(h_lds[0], h_lds[1], t);
        cellE(h_lds[1], h_lds[0], t + 1);
    }

    // ========== transition: fold fc into weights =========
    // W_eff = gs*(W_hh + W_ih*fc_w) ; b_eff = gs*(b + W_ih*fc_b) (exact fp32, C-layout)
#pragma unroll
    for (int g = 0; g < 4; ++g) {
        beff[g] = bc[g] + w0c[g] * fcb0 + w1c[g] * fcb1;
        const int cg2 = g * HIDDEN + ub;                    // A-layout col for weight fold
        const float wi0 = W_ih[cg2 * 2 + 0];
        const float wi1 = W_ih[cg2 * 2 + 1];
#pragma unroll
        for (int ks = 0; ks < 4; ++ks) {
            const int k0 = ks * 32 + quad * 8;
            bf16x8 bb = bfrag[g][ks];
#pragma unroll
            for (int j = 0; j < 8; ++j)
                bb[j] = (__bf16)((float)bb[j] + gs[g] * (wi0 * fcw_lds[0][k0 + j]
                                                       + wi1 * fcw_lds[1][k0 + j]));
            bfrag[g][ks] = bb;
        }
    }

    auto cellF = [&](const __bf16* hs, __bf16* hd) {
        cellCore(hs, hd, beff[0], beff[1], beff[2], beff[3]);
    };

    // y output only (no feedback): wave0 computes while others run MFMA
    auto emitY = [&](const __bf16* hs, int f) {
        if (wave == 0) {
            const int r = lane & 15, seg = lane >> 4;
            const __bf16* hp = &hs[r * HPITCH + seg * 32];
            float p0 = 0.f, p1 = 0.f;
#pragma unroll
            for (int js = 0; js < 4; ++js) {
                bf16x8 hv = *(const bf16x8*)&hp[js * 8];
                const float4* f0 = (const float4*)&fcw_lds[0][seg * 32 + js * 8];
                const float4* f1 = (const float4*)&fcw_lds[1][seg * 32 + js * 8];
                float4 a0 = f0[0], b0 = f0[1], a1 = f1[0], b1 = f1[1];
                p0 += (float)hv[0]*a0.x + (float)hv[1]*a0.y + (float)hv[2]*a0.z + (float)hv[3]*a0.w
                    + (float)hv[4]*b0.x + (float)hv[5]*b0.y + (float)hv[6]*b0.z + (float)hv[7]*b0.w;
                p1 += (float)hv[0]*a1.x + (float)hv[1]*a1.y + (float)hv[2]*a1.z + (float)hv[3]*a1.w
                    + (float)hv[4]*b1.x + (float)hv[5]*b1.y + (float)hv[6]*b1.z + (float)hv[7]*b1.w;
            }
            p0 += __shfl_xor(p0, 16); p0 += __shfl_xor(p0, 32);
            p1 += __shfl_xor(p1, 16); p1 += __shfl_xor(p1, 32);
            if (seg == 0) {
                float* op = &out[(size_t)(rb + r) * (2 * NFUT) + f * 2];
                op[0] = p0 + fcb0;
                op[1] = p1 + fcb1;
            }
        }
    };

    // ================= forecast: 50 steps ================
    for (int f = 0; f < NFUT; f += 2) {
        emitY(h_lds[0], f);
        cellF(h_lds[0], h_lds[1]);
        emitY(h_lds[1], f + 1);
        cellF(h_lds[1], h_lds[0]);
    }
}

extern "C" void kernel_launch(void* const* d_in, const int* in_sizes, int n_in,
                              void* d_out, int out_size, void* d_ws, size_t ws_size,
                              hipStream_t stream) {
    const float* x    = (const float*)d_in[0];
    const float* W_ih = (const float*)d_in[1];
    const float* W_hh = (const float*)d_in[2];
    const float* b_ih = (const float*)d_in[3];
    const float* b_hh = (const float*)d_in[4];
    const float* fc_w = (const float*)d_in[5];
    const float* fc_b = (const float*)d_in[6];
    float* out = (float*)d_out;

    const int B = in_sizes[0] / (TSTEPS * 2);   // 4096
    const int grid = B / BR;                    // 256 blocks, 1 per CU
    lstm_forecast_kernel<<<grid, THREADS, 0, stream>>>(x, W_ih, W_hh, b_ih, b_hh, fc_w, fc_b, out);
}

// Round 3
// 477.581 us; speedup vs baseline: 1.1890x; 1.0904x over previous
//
#include <hip/hip_runtime.h>

#define HIDDEN 128
#define TSTEPS 512
#define NFUT 50
#define BR 16          // batch rows per block
#define THREADS 512    // 8 waves, 2/SIMD
#define HPITCH 136     // h row pitch in bf16 (272B rows: 16B-aligned for b128)

typedef __bf16 bf16x8 __attribute__((ext_vector_type(8)));
typedef float floatx4 __attribute__((ext_vector_type(4)));
typedef float f32x2 __attribute__((ext_vector_type(2)));

union B8 { int4 i; bf16x8 v; };

#if defined(__has_builtin)
#  if __has_builtin(__builtin_amdgcn_exp2f)
#    define EXP2F(x) __builtin_amdgcn_exp2f(x)
#  else
#    define EXP2F(x) exp2f(x)
#  endif
#  if __has_builtin(__builtin_amdgcn_rcpf)
#    define RCPF(x) __builtin_amdgcn_rcpf(x)
#  else
#    define RCPF(x) (1.0f / (x))
#  endif
#  if __has_builtin(__builtin_amdgcn_s_setprio)
#    define SETPRIO(p) __builtin_amdgcn_s_setprio(p)
#  else
#    define SETPRIO(p)
#  endif
#else
#  define EXP2F(x) exp2f(x)
#  define RCPF(x) (1.0f / (x))
#  define SETPRIO(p)
#endif

#define L2E  1.4426950408889634f
#define L2E2 2.8853900817779268f

__global__ __launch_bounds__(THREADS, 2)
void lstm_forecast_kernel(const float* __restrict__ x,
                          const float* __restrict__ W_ih,
                          const float* __restrict__ W_hh,
                          const float* __restrict__ b_ih,
                          const float* __restrict__ b_hh,
                          const float* __restrict__ fc_w,
                          const float* __restrict__ fc_b,
                          float* __restrict__ out) {
    // LDS: xa 64KB + h 8.5KB + fcw 1KB ~= 74KB -> 1 block/CU
    __shared__ __align__(16) uint2  xa[TSTEPS * BR];        // (x0h,x1h),(x0r,x1r) bf16 splits
    __shared__ __align__(16) __bf16 h_lds[2][BR * HPITCH];  // double-buffered h
    __shared__ __align__(16) float  fcw_lds[2][HIDDEN];

    const int tid  = threadIdx.x;
    const int wave = tid >> 6;          // 0..7, 2 waves share a SIMD
    const int lane = tid & 63;
    const int quad = lane >> 4;
    const int l15  = lane & 15;
    const int rb   = blockIdx.x * BR;

    if (tid < 256) fcw_lds[tid >> 7][tid & 127] = fc_w[tid];

    // ---- stage x as bf16 hi/lo splits: xa[t][row] (feeds the x-MFMA) ----
    {
        const int row = tid & 15;
        for (int tb = tid >> 4; tb < TSTEPS; tb += THREADS >> 4) {
            float2 xv = *(const float2*)&x[(size_t)(rb + row) * (2 * TSTEPS) + tb * 2];
            __bf16 x0h = (__bf16)xv.x, x1h = (__bf16)xv.y;
            __bf16 x0r = (__bf16)(xv.x - (float)x0h);
            __bf16 x1r = (__bf16)(xv.y - (float)x1h);
            uint2 d;
            d.x = (unsigned)__builtin_bit_cast(unsigned short, x0h) |
                  ((unsigned)__builtin_bit_cast(unsigned short, x1h) << 16);
            d.y = (unsigned)__builtin_bit_cast(unsigned short, x0r) |
                  ((unsigned)__builtin_bit_cast(unsigned short, x1r) << 16);
            xa[tb * BR + row] = d;
        }
    }
    for (int i = tid; i < BR * HPITCH; i += THREADS) h_lds[0][i] = (__bf16)0.0f;

    // ---- weights -> registers, pre-scaled so MFMA outputs are exp2-ready ----
    // gate scale: i,f,o -> -log2(e); g -> -2*log2(e)
    // Transposed MFMA: bfrag/bfx = A operand (m = gate col = wave*16 + l15),
    // h/x = B operand (n = batch row = l15).
    // C layout: n(=lane&15) = batch row, m(=quad*4+reg) = gate-col offset.
    bf16x8 bfrag[4][4];   // [gate][kchunk] scaled W_hh (later W_eff)
    B8 bfx[4];            // scaled W_ih + bias hi/lo, quad0 k-slots only (A operand)
    float gs[4];
    const float fcb0 = fc_b[0], fcb1 = fc_b[1];
    const int ub    = wave * 16 + l15;        // A-layout gate col (weights)
    const int cbase = wave * 16 + quad * 4;   // C-layout gate-col base (ew/h-write)
#pragma unroll
    for (int g = 0; g < 4; ++g) {
        gs[g] = (g == 2) ? -L2E2 : -L2E;
        const int cg = g * HIDDEN + ub;
        const float w0 = W_ih[cg * 2 + 0];
        const float w1 = W_ih[cg * 2 + 1];
        const float bs = b_ih[cg] + b_hh[cg];
#pragma unroll
        for (int ks = 0; ks < 4; ++ks) {
            const float* wp = W_hh + (size_t)cg * HIDDEN + ks * 32 + quad * 8;
            bf16x8 bb;
#pragma unroll
            for (int j = 0; j < 8; ++j) bb[j] = (__bf16)(gs[g] * wp[j]);
            bfrag[g][ks] = bb;
        }
        B8 t; t.i = make_int4(0, 0, 0, 0);
        if (quad == 0) {
            const float w0s = gs[g] * w0, w1s = gs[g] * w1, bss = gs[g] * bs;
            __bf16 w0h = (__bf16)w0s, w1h = (__bf16)w1s;
            __bf16 w0l = (__bf16)(w0s - (float)w0h);
            __bf16 w1l = (__bf16)(w1s - (float)w1h);
            __bf16 bh  = (__bf16)bss;
            __bf16 bl  = (__bf16)(bss - (float)bh);
            bf16x8 bv = {w0h, w1h, bh, bl, w0h, w1h, w0l, w1l};
            t.v = bv;
        }
        bfx[g] = t;
    }

    const unsigned ones2 = 0x3F803F80u;  // bf16(1.0) x2
    const int hrow = l15 * HPITCH;
    f32x2 cst[2] = {{0.f, 0.f}, {0.f, 0.f}};   // cell state: pair p = cols cbase+2p..+1

    auto pk2 = [](f32x2 hn) -> unsigned {
        return (unsigned)__builtin_bit_cast(unsigned short, (__bf16)hn.x)
             | ((unsigned)__builtin_bit_cast(unsigned short, (__bf16)hn.y) << 16);
    };

    // ew tail: 16 gate exps, then per-pair combine (tanh-c exp inline), pack, b64 write.
    auto ewTail = [&](floatx4 a0, floatx4 a1, floatx4 a2, floatx4 a3, __bf16* hd) {
        floatx4 ea, ec, eb, eo;
#pragma unroll
        for (int r = 0; r < 4; ++r) ea[r] = EXP2F(a0[r]);   // e^-i
#pragma unroll
        for (int r = 0; r < 4; ++r) ec[r] = EXP2F(a1[r]);   // e^-f
#pragma unroll
        for (int r = 0; r < 4; ++r) eb[r] = EXP2F(a2[r]);   // e^-2g
#pragma unroll
        for (int r = 0; r < 4; ++r) eo[r] = EXP2F(a3[r]);   // e^-o
        unsigned wArr[2];
#pragma unroll
        for (int p = 0; p < 2; ++p) {
            const f32x2 eap = {ea[2 * p], ea[2 * p + 1]};
            const f32x2 ebp = {eb[2 * p], eb[2 * p + 1]};
            const f32x2 ecp = {ec[2 * p], ec[2 * p + 1]};
            const f32x2 eop = {eo[2 * p], eo[2 * p + 1]};
            const f32x2 A1 = 1.f + eap, B1 = 1.f + ebp, C1 = 1.f + ecp;
            const f32x2 P  = A1 * B1;
            const f32x2 PC = P * C1;
            f32x2 R;                                        // batched: 1 rcp per pair
            { const float I = RCPF(PC.x * PC.y); R.x = I * PC.y; R.y = I * PC.x; }
            const f32x2 sfv = P * R;                        // sigmoid(f)
            const f32x2 igv = (1.f - ebp) * (C1 * R);       // sigmoid(i)*tanh(g)
            const f32x2 cn  = sfv * cst[p] + igv;
            cst[p] = cn;
            const f32x2 am = -L2E2 * cn;
            f32x2 ed;
            ed.x = EXP2F(fminf(am.x, 29.f));                // c clamped at -10 (tanh err < 4e-9)
            ed.y = EXP2F(fminf(am.y, 29.f));
            const f32x2 E = (1.f + ed) * (1.f + eop);
            f32x2 R2;                                       // batched: 1 rcp per pair
            { const float J = RCPF(E.x * E.y); R2.x = J * E.y; R2.y = J * E.x; }
            const f32x2 hn = (1.f - ed) * R2;               // sigmoid(o)*tanh(c)
            wArr[p] = pk2(hn);
        }
        uint2 wv; wv.x = wArr[0]; wv.y = wArr[1];
        *(uint2*)&hd[hrow + cbase] = wv;                    // 4 cols, one b64
    };

    // Encode cell: x+bias via MFMA on the (underused) matrix pipe; ks-outer/g-inner
    // gives 4 independent accumulation chains (issue-spacing ~5cy, not chained-stall).
    // Prefetch next step's xa (h-independent) so its LDS latency drains under ew+barrier.
    auto cellE = [&](const __bf16* hs, __bf16* hd, uint2 xd, int tn) -> uint2 {
        B8 xf; xf.i = make_int4((int)xd.x, (int)ones2, (int)xd.y, (int)xd.x);
        bf16x8 af[4];
#pragma unroll
        for (int ks = 0; ks < 4; ++ks)
            af[ks] = *(const bf16x8*)&hs[hrow + ks * 32 + quad * 8];
        const floatx4 z = {0.f, 0.f, 0.f, 0.f};
        floatx4 acc[4];
        SETPRIO(1);
#pragma unroll
        for (int g = 0; g < 4; ++g)
            acc[g] = __builtin_amdgcn_mfma_f32_16x16x32_bf16(bfx[g].v, xf.v, z, 0, 0, 0);
#pragma unroll
        for (int ks = 0; ks < 4; ++ks)
#pragma unroll
            for (int g = 0; g < 4; ++g)
                acc[g] = __builtin_amdgcn_mfma_f32_16x16x32_bf16(bfrag[g][ks], af[ks], acc[g], 0, 0, 0);
        SETPRIO(0);
        const int ts = (tn < TSTEPS) ? tn : 0;
        const uint2 xn = xa[ts * BR + l15];                 // prefetch (consumed next cell)
        ewTail(acc[0], acc[1], acc[2], acc[3], hd);
        __syncthreads();
        return xn;
    };

    __syncthreads();

    // ================= encode: 512 steps =================
    uint2 xd = xa[l15];                                     // t = 0
    for (int t = 0; t < TSTEPS; t += 2) {
        xd = cellE(h_lds[0], h_lds[1], xd, t + 1);
        xd = cellE(h_lds[1], h_lds[0], xd, t + 2);
    }

    // ========== transition: fold fc into weights =========
    // W_eff = gs*(W_hh + W_ih*fc_w) (A-layout fold); b_eff in exact fp32 C-layout.
    floatx4 beff[4];
#pragma unroll
    for (int g = 0; g < 4; ++g) {
        const int cgA = g * HIDDEN + ub;
        const float wi0 = W_ih[cgA * 2 + 0];
        const float wi1 = W_ih[cgA * 2 + 1];
#pragma unroll
        for (int ks = 0; ks < 4; ++ks) {
            const int k0 = ks * 32 + quad * 8;
            bf16x8 bb = bfrag[g][ks];
#pragma unroll
            for (int j = 0; j < 8; ++j)
                bb[j] = (__bf16)((float)bb[j] + gs[g] * (wi0 * fcw_lds[0][k0 + j]
                                                       + wi1 * fcw_lds[1][k0 + j]));
            bfrag[g][ks] = bb;
        }
        floatx4 v;
#pragma unroll
        for (int r = 0; r < 4; ++r) {
            const int cg = g * HIDDEN + cbase + r;          // C-layout col
            v[r] = gs[g] * (b_ih[cg] + b_hh[cg]
                          + W_ih[cg * 2 + 0] * fcb0 + W_ih[cg * 2 + 1] * fcb1);
        }
        beff[g] = v;
    }

    auto cellF = [&](const __bf16* hs, __bf16* hd) {
        bf16x8 af[4];
#pragma unroll
        for (int ks = 0; ks < 4; ++ks)
            af[ks] = *(const bf16x8*)&hs[hrow + ks * 32 + quad * 8];
        floatx4 acc[4];
#pragma unroll
        for (int g = 0; g < 4; ++g) acc[g] = beff[g];       // exact fp32 scaled bias
        SETPRIO(1);
#pragma unroll
        for (int ks = 0; ks < 4; ++ks)
#pragma unroll
            for (int g = 0; g < 4; ++g)
                acc[g] = __builtin_amdgcn_mfma_f32_16x16x32_bf16(bfrag[g][ks], af[ks], acc[g], 0, 0, 0);
        SETPRIO(0);
        ewTail(acc[0], acc[1], acc[2], acc[3], hd);
        __syncthreads();
    };

    // y output only (no feedback): wave0 computes while others run MFMA
    auto emitY = [&](const __bf16* hs, int f) {
        if (wave == 0) {
            const int r = lane & 15, seg = lane >> 4;
            const __bf16* hp = &hs[r * HPITCH + seg * 32];
            float p0 = 0.f, p1 = 0.f;
#pragma unroll
            for (int js = 0; js < 4; ++js) {
                bf16x8 hv = *(const bf16x8*)&hp[js * 8];
                const float4* f0 = (const float4*)&fcw_lds[0][seg * 32 + js * 8];
                const float4* f1 = (const float4*)&fcw_lds[1][seg * 32 + js * 8];
                float4 a0 = f0[0], b0 = f0[1], a1 = f1[0], b1 = f1[1];
                p0 += (float)hv[0]*a0.x + (float)hv[1]*a0.y + (float)hv[2]*a0.z + (float)hv[3]*a0.w
                    + (float)hv[4]*b0.x + (float)hv[5]*b0.y + (float)hv[6]*b0.z + (float)hv[7]*b0.w;
                p1 += (float)hv[0]*a1.x + (float)hv[1]*a1.y + (float)hv[2]*a1.z + (float)hv[3]*a1.w
                    + (float)hv[4]*b1.x + (float)hv[5]*b1.y + (float)hv[6]*b1.z + (float)hv[7]*b1.w;
            }
            p0 += __shfl_xor(p0, 16); p0 += __shfl_xor(p0, 32);
            p1 += __shfl_xor(p1, 16); p1 += __shfl_xor(p1, 32);
            if (seg == 0) {
                float* op = &out[(size_t)(rb + r) * (2 * NFUT) + f * 2];
                op[0] = p0 + fcb0;
                op[1] = p1 + fcb1;
            }
        }
    };

    // ================= forecast: 50 steps ================
    for (int f = 0; f < NFUT; f += 2) {
        emitY(h_lds[0], f);
        cellF(h_lds[0], h_lds[1]);
        emitY(h_lds[1], f + 1);
        cellF(h_lds[1], h_lds[0]);
    }
}

extern "C" void kernel_launch(void* const* d_in, const int* in_sizes, int n_in,
                              void* d_out, int out_size, void* d_ws, size_t ws_size,
                              hipStream_t stream) {
    const float* x    = (const float*)d_in[0];
    const float* W_ih = (const float*)d_in[1];
    const float* W_hh = (const float*)d_in[2];
    const float* b_ih = (const float*)d_in[3];
    const float* b_hh = (const float*)d_in[4];
    const float* fc_w = (const float*)d_in[5];
    const float* fc_b = (const float*)d_in[6];
    float* out = (float*)d_out;

    const int B = in_sizes[0] / (TSTEPS * 2);   // 4096
    const int grid = B / BR;                    // 256 blocks, 1 per CU
    lstm_forecast_kernel<<<grid, THREADS, 0, stream>>>(x, W_ih, W_hh, b_ih, b_hh, fc_w, fc_b, out);
}